// Round 1
// baseline (2273.510 us; speedup 1.0000x reference)
//
#include <hip/hip_runtime.h>
#include <hip/hip_bf16.h>

// Problem constants
#define BATCH 2
#define CIN   1024      // C
#define NN    2048      // sequence length N
#define HEADS 16
#define DHEAD 64
#define HDIM  1024      // HEADS*DHEAD
#define O3    3072      // 3*HDIM
#define SCALE 0.125f    // DHEAD^-0.5

// ---------------- GEMM: C[b,m,n] = sum_c A[m,c] * B[b,c,n] (+ bias[m]) ----------------
#define BM 128
#define BN 128
#define BK 8

__global__ __launch_bounds__(256) void gemm_f32(const float* __restrict__ A,
                                                const float* __restrict__ B,
                                                const float* __restrict__ bias,
                                                float* __restrict__ C,
                                                int M, int K, int Nn) {
    __shared__ float As[BK][BM];
    __shared__ float Bs[BK][BN];

    const int b = blockIdx.z;
    const float* Bb = B + (size_t)b * K * Nn;
    float* Cb = C + (size_t)b * M * Nn;

    const int m0 = blockIdx.y * BM;
    const int n0 = blockIdx.x * BN;
    const int tid = threadIdx.x;

    // A tile load: 128 rows x 8 k; one float4 per thread
    const int arow = tid >> 1;
    const int acol = (tid & 1) * 4;
    // B tile load: 8 k-rows x 128 n; one float4 per thread
    const int brow = tid >> 5;
    const int bcol = (tid & 31) * 4;

    // compute mapping: 16x16 threads, 8x8 outputs each
    const int tm = (tid >> 4) * 8;
    const int tn = (tid & 15) * 8;

    float acc[8][8] = {};

    for (int k0 = 0; k0 < K; k0 += BK) {
        float4 av = *(const float4*)&A[(size_t)(m0 + arow) * K + k0 + acol];
        float4 bv = *(const float4*)&Bb[(size_t)(k0 + brow) * Nn + n0 + bcol];
        __syncthreads();  // previous iteration readers done
        As[acol + 0][arow] = av.x;
        As[acol + 1][arow] = av.y;
        As[acol + 2][arow] = av.z;
        As[acol + 3][arow] = av.w;
        *(float4*)&Bs[brow][bcol] = bv;
        __syncthreads();
#pragma unroll
        for (int k = 0; k < BK; ++k) {
            float4 a0 = *(const float4*)&As[k][tm];
            float4 a1 = *(const float4*)&As[k][tm + 4];
            float4 b0 = *(const float4*)&Bs[k][tn];
            float4 b1 = *(const float4*)&Bs[k][tn + 4];
            float am[8] = {a0.x, a0.y, a0.z, a0.w, a1.x, a1.y, a1.z, a1.w};
            float bn_[8] = {b0.x, b0.y, b0.z, b0.w, b1.x, b1.y, b1.z, b1.w};
#pragma unroll
            for (int i = 0; i < 8; ++i)
#pragma unroll
                for (int j = 0; j < 8; ++j)
                    acc[i][j] += am[i] * bn_[j];
        }
    }

#pragma unroll
    for (int i = 0; i < 8; ++i) {
        float bi = bias ? bias[m0 + tm + i] : 0.0f;
        float4 r0 = {acc[i][0] + bi, acc[i][1] + bi, acc[i][2] + bi, acc[i][3] + bi};
        float4 r1 = {acc[i][4] + bi, acc[i][5] + bi, acc[i][6] + bi, acc[i][7] + bi};
        *(float4*)&Cb[(size_t)(m0 + tm + i) * Nn + n0 + tn]     = r0;
        *(float4*)&Cb[(size_t)(m0 + tm + i) * Nn + n0 + tn + 4] = r1;
    }
}

// ---------------- Attention: thread-per-query-row online softmax ----------------
#define JC 16  // key chunk

__global__ __launch_bounds__(256) void attn_f32(const float* __restrict__ qkv,
                                                float* __restrict__ ao) {
    const int b = blockIdx.z;
    const int h = blockIdx.y;
    const int i = blockIdx.x * 256 + threadIdx.x;  // query index (always < NN)

    const float* Q = qkv + ((size_t)b * O3 + h * DHEAD) * NN;
    const float* K = qkv + ((size_t)b * O3 + HDIM + h * DHEAD) * NN;
    const float* V = qkv + ((size_t)b * O3 + 2 * HDIM + h * DHEAD) * NN;

    float q[DHEAD];
#pragma unroll
    for (int d = 0; d < DHEAD; ++d) q[d] = Q[(size_t)d * NN + i] * SCALE;

    float acc[DHEAD] = {};
    float mrow = -1e30f, lrow = 0.0f;

    __shared__ float Ks[JC][DHEAD];  // [j][d]
    __shared__ float Vs[JC][DHEAD];

    const int ld = threadIdx.x >> 2;        // 0..63 : d index
    const int lj = (threadIdx.x & 3) * 4;   // 0,4,8,12 : j quad

    for (int j0 = 0; j0 < NN; j0 += JC) {
        float4 kv = *(const float4*)&K[(size_t)ld * NN + j0 + lj];
        float4 vv = *(const float4*)&V[(size_t)ld * NN + j0 + lj];
        __syncthreads();
        Ks[lj + 0][ld] = kv.x; Ks[lj + 1][ld] = kv.y;
        Ks[lj + 2][ld] = kv.z; Ks[lj + 3][ld] = kv.w;
        Vs[lj + 0][ld] = vv.x; Vs[lj + 1][ld] = vv.y;
        Vs[lj + 2][ld] = vv.z; Vs[lj + 3][ld] = vv.w;
        __syncthreads();

        float s[JC];
        float cmax = mrow;
#pragma unroll
        for (int jj = 0; jj < JC; ++jj) {
            float d0 = 0.f, d1 = 0.f, d2 = 0.f, d3 = 0.f;
#pragma unroll
            for (int d4 = 0; d4 < DHEAD; d4 += 4) {
                float4 k4 = *(const float4*)&Ks[jj][d4];
                d0 += q[d4 + 0] * k4.x;
                d1 += q[d4 + 1] * k4.y;
                d2 += q[d4 + 2] * k4.z;
                d3 += q[d4 + 3] * k4.w;
            }
            float dot = (d0 + d1) + (d2 + d3);
            s[jj] = dot;
            cmax = fmaxf(cmax, dot);
        }
        float corr = __expf(mrow - cmax);
        lrow *= corr;
#pragma unroll
        for (int d = 0; d < DHEAD; ++d) acc[d] *= corr;
        mrow = cmax;
#pragma unroll
        for (int jj = 0; jj < JC; ++jj) {
            float p = __expf(s[jj] - cmax);
            lrow += p;
#pragma unroll
            for (int d4 = 0; d4 < DHEAD; d4 += 4) {
                float4 v4 = *(const float4*)&Vs[jj][d4];
                acc[d4 + 0] += p * v4.x;
                acc[d4 + 1] += p * v4.y;
                acc[d4 + 2] += p * v4.z;
                acc[d4 + 3] += p * v4.w;
            }
        }
    }

    const float inv_l = 1.0f / lrow;
#pragma unroll
    for (int d = 0; d < DHEAD; ++d)
        ao[((size_t)b * HDIM + h * DHEAD + d) * NN + i] = acc[d] * inv_l;
}

// ---------------- launch ----------------
extern "C" void kernel_launch(void* const* d_in, const int* in_sizes, int n_in,
                              void* d_out, int out_size, void* d_ws, size_t ws_size,
                              hipStream_t stream) {
    const float* x     = (const float*)d_in[0];  // [B, C, N]
    const float* w_qkv = (const float*)d_in[1];  // [3*HDIM, C]
    const float* w_out = (const float*)d_in[2];  // [C, HDIM]
    const float* b_out = (const float*)d_in[3];  // [C]
    float* out = (float*)d_out;                  // [B, C, N]

    const size_t qkv_elems = (size_t)BATCH * O3 * NN;      // 12.58M floats
    const size_t ao_elems  = (size_t)BATCH * HDIM * NN;    // 4.19M floats
    if (ws_size < (qkv_elems + ao_elems) * sizeof(float)) return;  // loud failure

    float* qkv = (float*)d_ws;
    float* ao  = qkv + qkv_elems;

    // 1) qkv[b,o,n] = sum_c w_qkv[o,c] * x[b,c,n]
    gemm_f32<<<dim3(NN / BN, O3 / BM, BATCH), 256, 0, stream>>>(
        w_qkv, x, nullptr, qkv, O3, CIN, NN);

    // 2) attention -> ao[b, h*64+d, n]
    attn_f32<<<dim3(NN / 256, HEADS, BATCH), 256, 0, stream>>>(qkv, ao);

    // 3) out[b,o,n] = b_out[o] + sum_c w_out[o,c] * ao[b,c,n]
    gemm_f32<<<dim3(NN / BN, HDIM / BM, BATCH), 256, 0, stream>>>(
        w_out, ao, b_out, out, HDIM, CIN, NN);
}

// Round 2
// 700.081 us; speedup vs baseline: 3.2475x; 3.2475x over previous
//
#include <hip/hip_runtime.h>
#include <hip/hip_bf16.h>

// Problem constants
#define BATCH 2
#define CIN   1024
#define NN    2048
#define HEADS 16
#define DHEAD 64
#define HDIM  1024
#define O3    3072
#define QSCALE 0.125f

typedef __attribute__((ext_vector_type(8))) short bf16x8;
typedef __attribute__((ext_vector_type(8))) unsigned short ushort8;
typedef __attribute__((ext_vector_type(16))) float f32x16;

__device__ inline unsigned short f2bf(float f) {
    unsigned u = __builtin_bit_cast(unsigned, f);
    unsigned r = u + 0x7fffu + ((u >> 16) & 1u);
    return (unsigned short)(r >> 16);
}
__device__ inline float bf2f(unsigned short h) {
    return __builtin_bit_cast(float, (unsigned)h << 16);
}

__device__ inline f32x16 mfma32(bf16x8 a, bf16x8 b, f32x16 c) {
    return __builtin_amdgcn_mfma_f32_32x32x16_bf16(a, b, c, 0, 0, 0);
}

union U4 { unsigned u[4]; bf16x8 v; };

// ---------------- GEMM (f32): C[b,m,n] = sum_c A[m,c]*B[b,c,n] (+bias) ----------------
#define BM 128
#define BN 128
#define BK 8

__global__ __launch_bounds__(256) void gemm_f32(const float* __restrict__ A,
                                                const float* __restrict__ B,
                                                const float* __restrict__ bias,
                                                float* __restrict__ C,
                                                int M, int K, int Nn) {
    __shared__ float As[BK][BM];
    __shared__ float Bs[BK][BN];

    const int b = blockIdx.z;
    const float* Bb = B + (size_t)b * K * Nn;
    float* Cb = C + (size_t)b * M * Nn;

    const int m0 = blockIdx.y * BM;
    const int n0 = blockIdx.x * BN;
    const int tid = threadIdx.x;

    const int arow = tid >> 1;
    const int acol = (tid & 1) * 4;
    const int brow = tid >> 5;
    const int bcol = (tid & 31) * 4;
    const int tm = (tid >> 4) * 8;
    const int tn = (tid & 15) * 8;

    float acc[8][8] = {};

    for (int k0 = 0; k0 < K; k0 += BK) {
        float4 av = *(const float4*)&A[(size_t)(m0 + arow) * K + k0 + acol];
        float4 bv = *(const float4*)&Bb[(size_t)(k0 + brow) * Nn + n0 + bcol];
        __syncthreads();
        As[acol + 0][arow] = av.x;
        As[acol + 1][arow] = av.y;
        As[acol + 2][arow] = av.z;
        As[acol + 3][arow] = av.w;
        *(float4*)&Bs[brow][bcol] = bv;
        __syncthreads();
#pragma unroll
        for (int k = 0; k < BK; ++k) {
            float4 a0 = *(const float4*)&As[k][tm];
            float4 a1 = *(const float4*)&As[k][tm + 4];
            float4 b0 = *(const float4*)&Bs[k][tn];
            float4 b1 = *(const float4*)&Bs[k][tn + 4];
            float am[8] = {a0.x, a0.y, a0.z, a0.w, a1.x, a1.y, a1.z, a1.w};
            float bn_[8] = {b0.x, b0.y, b0.z, b0.w, b1.x, b1.y, b1.z, b1.w};
#pragma unroll
            for (int i = 0; i < 8; ++i)
#pragma unroll
                for (int j = 0; j < 8; ++j)
                    acc[i][j] += am[i] * bn_[j];
        }
    }

#pragma unroll
    for (int i = 0; i < 8; ++i) {
        float bi = bias ? bias[m0 + tm + i] : 0.0f;
        float4 r0 = {acc[i][0] + bi, acc[i][1] + bi, acc[i][2] + bi, acc[i][3] + bi};
        float4 r1 = {acc[i][4] + bi, acc[i][5] + bi, acc[i][6] + bi, acc[i][7] + bi};
        *(float4*)&Cb[(size_t)(m0 + tm + i) * Nn + n0 + tn]     = r0;
        *(float4*)&Cb[(size_t)(m0 + tm + i) * Nn + n0 + tn + 4] = r1;
    }
}

// ------------- QKV GEMM: same loop, epilogue writes bf16 hi/lo split ---------------
// Q rows [0,1024):    Qh/Ql  [bh][n][64]  (transposed, scaled by QSCALE)
// K rows [1024,2048): Kh/Kl  [bh][n][64]  (transposed)
// V rows [2048,3072): Vh/Vl  [b*1024+ch][n] (channel-major, as-is)
#define QSZ ((size_t)BATCH * HEADS * NN * DHEAD)  // 4194304 elements per buffer

__global__ __launch_bounds__(256) void gemm_qkv(const float* __restrict__ A,
                                                const float* __restrict__ B,
                                                unsigned short* __restrict__ ws0) {
    __shared__ float As[BK][BM];
    __shared__ float Bs[BK][BN];

    const int b = blockIdx.z;
    const float* Bb = B + (size_t)b * CIN * NN;

    const int m0 = blockIdx.y * BM;
    const int n0 = blockIdx.x * BN;
    const int tid = threadIdx.x;

    const int arow = tid >> 1;
    const int acol = (tid & 1) * 4;
    const int brow = tid >> 5;
    const int bcol = (tid & 31) * 4;
    const int tm = (tid >> 4) * 8;
    const int tn = (tid & 15) * 8;

    float acc[8][8] = {};

    for (int k0 = 0; k0 < CIN; k0 += BK) {
        float4 av = *(const float4*)&A[(size_t)(m0 + arow) * CIN + k0 + acol];
        float4 bv = *(const float4*)&Bb[(size_t)(k0 + brow) * NN + n0 + bcol];
        __syncthreads();
        As[acol + 0][arow] = av.x;
        As[acol + 1][arow] = av.y;
        As[acol + 2][arow] = av.z;
        As[acol + 3][arow] = av.w;
        *(float4*)&Bs[brow][bcol] = bv;
        __syncthreads();
#pragma unroll
        for (int k = 0; k < BK; ++k) {
            float4 a0 = *(const float4*)&As[k][tm];
            float4 a1 = *(const float4*)&As[k][tm + 4];
            float4 b0 = *(const float4*)&Bs[k][tn];
            float4 b1 = *(const float4*)&Bs[k][tn + 4];
            float am[8] = {a0.x, a0.y, a0.z, a0.w, a1.x, a1.y, a1.z, a1.w};
            float bn_[8] = {b0.x, b0.y, b0.z, b0.w, b1.x, b1.y, b1.z, b1.w};
#pragma unroll
            for (int i = 0; i < 8; ++i)
#pragma unroll
                for (int j = 0; j < 8; ++j)
                    acc[i][j] += am[i] * bn_[j];
        }
    }

    unsigned short* Qh = ws0;
    unsigned short* Ql = ws0 + QSZ;
    unsigned short* Kh = ws0 + 2 * QSZ;
    unsigned short* Kl = ws0 + 3 * QSZ;
    unsigned short* Vh = ws0 + 4 * QSZ;
    unsigned short* Vl = ws0 + 5 * QSZ;

    const int mbase = m0 + tm;           // 8 consecutive output channels
    const int nbase = n0 + tn;           // 8 consecutive n
    const int region = mbase >> 10;      // 0=Q 1=K 2=V (BM=128 divides 1024)

    if (region < 2) {
        const float scale = (region == 0) ? QSCALE : 1.0f;
        unsigned short* H = (region == 0) ? Qh : Kh;
        unsigned short* L = (region == 0) ? Ql : Kl;
        const int ch = mbase & 1023;
        const int h = ch >> 6;
        const int d0 = ch & 63;          // multiple of 8
        const size_t rowbase = (size_t)(b * HEADS + h) * NN;
#pragma unroll
        for (int j = 0; j < 8; ++j) {
            ushort8 hv, lv;
#pragma unroll
            for (int i = 0; i < 8; ++i) {
                float f = acc[i][j] * scale;
                unsigned short hh = f2bf(f);
                hv[i] = hh;
                lv[i] = f2bf(f - bf2f(hh));
            }
            size_t off = (rowbase + nbase + j) * DHEAD + d0;
            *(ushort8*)(H + off) = hv;
            *(ushort8*)(L + off) = lv;
        }
    } else {
        const int ch = mbase & 1023;
        const size_t rbase = ((size_t)b * HDIM + ch) * NN + nbase;
#pragma unroll
        for (int i = 0; i < 8; ++i) {
            ushort8 hv, lv;
#pragma unroll
            for (int j = 0; j < 8; ++j) {
                float f = acc[i][j];
                unsigned short hh = f2bf(f);
                hv[j] = hh;
                lv[j] = f2bf(f - bf2f(hh));
            }
            *(ushort8*)(Vh + rbase + (size_t)i * NN) = hv;
            *(ushort8*)(Vl + rbase + (size_t)i * NN) = lv;
        }
    }
}

// ---------------- MFMA flash attention (no LDS, no barriers) ----------------
// Per wave: 32 queries. Swapped QK^T: S^T = K'.Q' (lane col = query).
// O^T = V^T . P^T accumulated in f32x16 pairs; online softmax per lane.
__global__ __launch_bounds__(256) void attn_mfma(
    const unsigned short* __restrict__ Qh, const unsigned short* __restrict__ Ql,
    const unsigned short* __restrict__ Kh, const unsigned short* __restrict__ Kl,
    const unsigned short* __restrict__ Vh, const unsigned short* __restrict__ Vl,
    float* __restrict__ ao) {
    const int b = blockIdx.z, h = blockIdx.y;
    const int bh = b * HEADS + h;
    const int wave = threadIdx.x >> 6;
    const int lane = threadIdx.x & 63;
    const int l31 = lane & 31;
    const int hi5 = lane >> 5;
    const int q0 = blockIdx.x * 128 + wave * 32;

    // Q B-fragments: col i = l31 (query q0+l31), k = c*16 + hi5*8 + t
    bf16x8 qfh[4], qfl[4];
    {
        const unsigned short* qb = Qh + ((size_t)bh * NN + q0 + l31) * DHEAD + hi5 * 8;
        const unsigned short* ql_ = Ql + ((size_t)bh * NN + q0 + l31) * DHEAD + hi5 * 8;
#pragma unroll
        for (int c = 0; c < 4; ++c) {
            qfh[c] = *(const bf16x8*)(qb + c * 16);
            qfl[c] = *(const bf16x8*)(ql_ + c * 16);
        }
    }

    f32x16 o0, o1;
#pragma unroll
    for (int r = 0; r < 16; ++r) { o0[r] = 0.f; o1[r] = 0.f; }
    float m = -1e30f, l = 0.f;

    const unsigned short* kbh = Kh + ((size_t)bh * NN + l31) * DHEAD + hi5 * 8;
    const unsigned short* kbl = Kl + ((size_t)bh * NN + l31) * DHEAD + hi5 * 8;
    const unsigned short* vbh = Vh + (size_t)bh * DHEAD * NN + hi5 * 8;
    const unsigned short* vbl = Vl + (size_t)bh * DHEAD * NN + hi5 * 8;

    for (int j0 = 0; j0 < NN; j0 += 32) {
        // ---- S^T tile: rows j (regs), cols i=queries (lanes) ----
        f32x16 s;
#pragma unroll
        for (int r = 0; r < 16; ++r) s[r] = 0.f;
#pragma unroll
        for (int c = 0; c < 4; ++c) {
            bf16x8 kh_ = *(const bf16x8*)(kbh + (size_t)j0 * DHEAD + c * 16);
            bf16x8 kl_ = *(const bf16x8*)(kbl + (size_t)j0 * DHEAD + c * 16);
            s = mfma32(kh_, qfh[c], s);   // hi*hi
            s = mfma32(kl_, qfh[c], s);   // lo*hi
            s = mfma32(kh_, qfl[c], s);   // hi*lo
        }

        // ---- online softmax (defer-max, THR=8) ----
        float tmax = s[0];
#pragma unroll
        for (int r = 1; r < 16; ++r) tmax = fmaxf(tmax, s[r]);
        tmax = fmaxf(tmax, __shfl_xor(tmax, 32));
        if (!__all(tmax - m <= 8.0f)) {
            float mn = fmaxf(m, tmax);
            float corr = __expf(m - mn);
            l *= corr;
#pragma unroll
            for (int r = 0; r < 16; ++r) { o0[r] *= corr; o1[r] *= corr; }
            m = mn;
        }
        float p[16];
        float ps = 0.f;
#pragma unroll
        for (int r = 0; r < 16; ++r) { p[r] = __expf(s[r] - m); ps += p[r]; }
        l += ps + __shfl_xor(ps, 32);

        // ---- pack P to bf16 hi/lo pairs ----
        unsigned phw[8], plw[8];
#pragma unroll
        for (int rp = 0; rp < 8; ++rp) {
            float a = p[2 * rp], c2 = p[2 * rp + 1];
            unsigned short ha = f2bf(a), hb = f2bf(c2);
            phw[rp] = (unsigned)ha | ((unsigned)hb << 16);
            unsigned short la = f2bf(a - bf2f(ha)), lb = f2bf(c2 - bf2f(hb));
            plw[rp] = (unsigned)la | ((unsigned)lb << 16);
        }

        // ---- PV: O^T += V^T . P^T ----
#pragma unroll
        for (int jc = 0; jc < 2; ++jc) {
            unsigned P0 = phw[4 * jc + 0], P1 = phw[4 * jc + 1];
            unsigned P2 = phw[4 * jc + 2], P3 = phw[4 * jc + 3];
            unsigned L0 = plw[4 * jc + 0], L1 = plw[4 * jc + 1];
            unsigned L2 = plw[4 * jc + 2], L3 = plw[4 * jc + 3];
            unsigned sP0 = __shfl_xor((int)P0, 32), sP1 = __shfl_xor((int)P1, 32);
            unsigned sP2 = __shfl_xor((int)P2, 32), sP3 = __shfl_xor((int)P3, 32);
            unsigned sL0 = __shfl_xor((int)L0, 32), sL1 = __shfl_xor((int)L1, 32);
            unsigned sL2 = __shfl_xor((int)L2, 32), sL3 = __shfl_xor((int)L3, 32);
            U4 th, tl;
            th.u[0] = hi5 ? sP2 : P0;
            th.u[1] = hi5 ? sP3 : P1;
            th.u[2] = hi5 ? P2 : sP0;
            th.u[3] = hi5 ? P3 : sP1;
            tl.u[0] = hi5 ? sL2 : L0;
            tl.u[1] = hi5 ? sL3 : L1;
            tl.u[2] = hi5 ? L2 : sL0;
            tl.u[3] = hi5 ? L3 : sL1;
            bf16x8 pBh = th.v, pBl = tl.v;
#pragma unroll
            for (int dt = 0; dt < 2; ++dt) {
                size_t voff = (size_t)(dt * 32 + l31) * NN + j0 + jc * 16;
                bf16x8 vh_ = *(const bf16x8*)(vbh + voff);
                bf16x8 vl_ = *(const bf16x8*)(vbl + voff);
                if (dt == 0) {
                    o0 = mfma32(vh_, pBh, o0);
                    o0 = mfma32(vh_, pBl, o0);
                    o0 = mfma32(vl_, pBh, o0);
                } else {
                    o1 = mfma32(vh_, pBh, o1);
                    o1 = mfma32(vh_, pBl, o1);
                    o1 = mfma32(vl_, pBh, o1);
                }
            }
        }
    }

    const float invl = 1.0f / l;
#pragma unroll
    for (int dt = 0; dt < 2; ++dt)
#pragma unroll
        for (int r = 0; r < 16; ++r) {
            int d = dt * 32 + (r & 3) + 8 * (r >> 2) + 4 * hi5;
            float val = (dt ? o1[r] : o0[r]) * invl;
            ao[((size_t)bh * DHEAD + d) * NN + q0 + l31] = val;
        }
}

// ---------------- launch ----------------
extern "C" void kernel_launch(void* const* d_in, const int* in_sizes, int n_in,
                              void* d_out, int out_size, void* d_ws, size_t ws_size,
                              hipStream_t stream) {
    const float* x     = (const float*)d_in[0];
    const float* w_qkv = (const float*)d_in[1];
    const float* w_out = (const float*)d_in[2];
    const float* b_out = (const float*)d_in[3];
    float* out = (float*)d_out;

    unsigned short* ws0 = (unsigned short*)d_ws;
    float* ao = (float*)((char*)d_ws + 6 * QSZ * sizeof(unsigned short));
    if (ws_size < 6 * QSZ * sizeof(unsigned short) + (size_t)BATCH * HDIM * NN * sizeof(float))
        return;

    // 1) QKV projection + bf16 hi/lo split (Q^T,K^T transposed; V channel-major)
    gemm_qkv<<<dim3(NN / BN, O3 / BM, BATCH), 256, 0, stream>>>(w_qkv, x, ws0);

    // 2) MFMA flash attention -> ao [b][h*64+d][n] f32
    attn_mfma<<<dim3(NN / 128, HEADS, BATCH), 256, 0, stream>>>(
        ws0, ws0 + QSZ, ws0 + 2 * QSZ, ws0 + 3 * QSZ, ws0 + 4 * QSZ, ws0 + 5 * QSZ, ao);

    // 3) output projection
    gemm_f32<<<dim3(NN / BN, HDIM / BM, BATCH), 256, 0, stream>>>(
        w_out, ao, b_out, out, HDIM, CIN, NN);
}

// Round 3
// 376.027 us; speedup vs baseline: 6.0461x; 1.8618x over previous
//
#include <hip/hip_runtime.h>
#include <hip/hip_bf16.h>

// Problem constants
#define BATCH 2
#define CIN   1024
#define NN    2048
#define HEADS 16
#define DHEAD 64
#define HDIM  1024
#define O3    3072
#define QSCALE 0.125f
#define QSZ ((size_t)BATCH * HEADS * NN * DHEAD)  // 4,194,304 elements

typedef unsigned short ushort_t;
typedef __attribute__((ext_vector_type(8))) short bf16x8;
typedef __attribute__((ext_vector_type(8))) unsigned short ushort8;
typedef __attribute__((ext_vector_type(4))) unsigned short ushort4v;
typedef __attribute__((ext_vector_type(16))) float f32x16;

__device__ inline ushort_t f2bf(float f) {
    unsigned u = __builtin_bit_cast(unsigned, f);
    unsigned r = u + 0x7fffu + ((u >> 16) & 1u);
    return (ushort_t)(r >> 16);
}
__device__ inline float bf2f(ushort_t h) {
    return __builtin_bit_cast(float, (unsigned)h << 16);
}
__device__ inline f32x16 mfma32(bf16x8 a, bf16x8 b, f32x16 c) {
    return __builtin_amdgcn_mfma_f32_32x32x16_bf16(a, b, c, 0, 0, 0);
}

union U4 { unsigned u[4]; bf16x8 v; };

// global -> LDS direct (16B per lane); LDS dest is wave-uniform base + lane*16
#define GLDS(gp, lp) __builtin_amdgcn_global_load_lds( \
    (__attribute__((address_space(1))) void*)(gp),     \
    (__attribute__((address_space(3))) void*)(lp), 16, 0, 0)

// ---------------- elementwise f32 -> bf16 hi/lo split ----------------
__global__ __launch_bounds__(256) void convert_split(const float* __restrict__ in,
                                                     ushort_t* __restrict__ hi,
                                                     ushort_t* __restrict__ lo,
                                                     int n8) {
    int t = blockIdx.x * 256 + threadIdx.x;
    if (t >= n8) return;
    size_t base = (size_t)t * 8;
    float4 a = *(const float4*)(in + base);
    float4 b = *(const float4*)(in + base + 4);
    float v[8] = {a.x, a.y, a.z, a.w, b.x, b.y, b.z, b.w};
    ushort8 hv, lv;
#pragma unroll
    for (int i = 0; i < 8; ++i) {
        ushort_t h = f2bf(v[i]);
        hv[i] = h;
        lv[i] = f2bf(v[i] - bf2f(h));
    }
    *(ushort8*)(hi + base) = hv;
    *(ushort8*)(lo + base) = lv;
}

// ------------- transpose + split: in f32 [B][CIN][NN] -> out hi/lo [B][NN][CIN] -------------
__global__ __launch_bounds__(256) void transpose_cvt(const float* __restrict__ in,
                                                     ushort_t* __restrict__ th,
                                                     ushort_t* __restrict__ tl) {
    __shared__ float T[32][33];
    const int b = blockIdx.z;
    const int n0 = blockIdx.x * 32, c0 = blockIdx.y * 32;
    const int t = threadIdx.x;
    const int r = t >> 3, q = t & 7;
    float4 v = *(const float4*)(in + ((size_t)b * CIN + c0 + r) * NN + n0 + q * 4);
    T[r][q * 4 + 0] = v.x; T[r][q * 4 + 1] = v.y;
    T[r][q * 4 + 2] = v.z; T[r][q * 4 + 3] = v.w;
    __syncthreads();
    ushort4v hv, lv;
#pragma unroll
    for (int i = 0; i < 4; ++i) {
        float f = T[q * 4 + i][r];
        ushort_t h = f2bf(f);
        hv[i] = h;
        lv[i] = f2bf(f - bf2f(h));
    }
    size_t o = ((size_t)b * NN + n0 + r) * CIN + c0 + q * 4;
    *(ushort4v*)(th + o) = hv;
    *(ushort4v*)(tl + o) = lv;
}

// ---------------- MFMA split-bf16 GEMM ----------------
// C[b,m,n] = sum_k (Ah+Al)[m,k] * (Bth+Btl)[b,n,k]  (3-term split product)
// MODE 0: QKV epilogue (writes Qh/Ql/Kh/Kl transposed-scaled, Vh/Vl channel-major)
// MODE 1: f32 out + bias
template<int MODE>
__global__ __launch_bounds__(256, 3) void gemm_mfma(
    const ushort_t* __restrict__ Ah, const ushort_t* __restrict__ Al,
    const ushort_t* __restrict__ Bth, const ushort_t* __restrict__ Btl,
    const float* __restrict__ bias, float* __restrict__ outF,
    ushort_t* __restrict__ Qh, ushort_t* __restrict__ Ql,
    ushort_t* __restrict__ Kh, ushort_t* __restrict__ Kl,
    ushort_t* __restrict__ Vh, ushort_t* __restrict__ Vl) {

    __shared__ __align__(16) ushort_t lsAh[4096], lsAl[4096], lsBh[4096], lsBl[4096];

    const int b  = blockIdx.z;
    const int n0 = blockIdx.x * 128;
    const int m0 = blockIdx.y * 128;
    const int tid = threadIdx.x;
    const int wave = tid >> 6, lane = tid & 63;
    const int l31 = lane & 31, hi5 = lane >> 5;
    const int wr = wave >> 1, wc = wave & 1;

    // ---- staging addresses (pre-swizzled global source; linear LDS dest) ----
    // lane covers 16B: row = chunk*16 + (lane>>2), k-offset swizzled by row bits 1-2
    const int srow = lane >> 2;
    const int kswz = 8 * ((lane & 3) ^ ((lane >> 3) & 3));
    const ushort_t* gAh = Ah  + (size_t)(m0 + wave * 16 + srow) * CIN + kswz;
    const ushort_t* gAl = Al  + (size_t)(m0 + wave * 16 + srow) * CIN + kswz;
    const ushort_t* gBh = Bth + ((size_t)b * NN + n0 + wave * 16 + srow) * CIN + kswz;
    const ushort_t* gBl = Btl + ((size_t)b * NN + n0 + wave * 16 + srow) * CIN + kswz;
    ushort_t* dAh = lsAh + wave * 512;
    ushort_t* dAl = lsAl + wave * 512;
    ushort_t* dBh = lsBh + wave * 512;
    ushort_t* dBl = lsBl + wave * 512;

    // ---- ds_read byte offsets (swizzle-matched) ----
    const int rswz = ((l31 >> 1) & 3) * 8;
    int offA[2][2], offB[2][2];
#pragma unroll
    for (int f = 0; f < 2; ++f)
#pragma unroll
        for (int kh = 0; kh < 2; ++kh) {
            offA[f][kh] = (wr * 64 + f * 32 + l31) * 64 + ((kh * 16 + hi5 * 8) ^ rswz) * 2;
            offB[f][kh] = (wc * 64 + f * 32 + l31) * 64 + ((kh * 16 + hi5 * 8) ^ rswz) * 2;
        }

    f32x16 acc[2][2];
#pragma unroll
    for (int i = 0; i < 2; ++i)
#pragma unroll
        for (int j = 0; j < 2; ++j)
#pragma unroll
            for (int r = 0; r < 16; ++r) acc[i][j][r] = 0.f;

    for (int k0 = 0; k0 < CIN; k0 += 32) {
        __syncthreads();   // previous compute done with LDS
        GLDS(gAh + k0,            dAh);
        GLDS(gAh + 64 * CIN + k0, dAh + 2048);
        GLDS(gAl + k0,            dAl);
        GLDS(gAl + 64 * CIN + k0, dAl + 2048);
        GLDS(gBh + k0,            dBh);
        GLDS(gBh + 64 * CIN + k0, dBh + 2048);
        GLDS(gBl + k0,            dBl);
        GLDS(gBl + 64 * CIN + k0, dBl + 2048);
        __syncthreads();   // compiler drains vmcnt before barrier
#pragma unroll
        for (int kh = 0; kh < 2; ++kh) {
            bf16x8 a_h[2], a_l[2], b_h[2], b_l[2];
#pragma unroll
            for (int f = 0; f < 2; ++f) {
                a_h[f] = *(const bf16x8*)((const char*)lsAh + offA[f][kh]);
                a_l[f] = *(const bf16x8*)((const char*)lsAl + offA[f][kh]);
                b_h[f] = *(const bf16x8*)((const char*)lsBh + offB[f][kh]);
                b_l[f] = *(const bf16x8*)((const char*)lsBl + offB[f][kh]);
            }
#pragma unroll
            for (int fi = 0; fi < 2; ++fi)
#pragma unroll
                for (int fj = 0; fj < 2; ++fj) {
                    acc[fi][fj] = mfma32(a_l[fi], b_h[fj], acc[fi][fj]);
                    acc[fi][fj] = mfma32(a_h[fi], b_l[fj], acc[fi][fj]);
                    acc[fi][fj] = mfma32(a_h[fi], b_h[fj], acc[fi][fj]);
                }
        }
    }

    const int nn = n0 + wc * 64 + l31;

    if constexpr (MODE == 0) {
        const int region = m0 >> 10;  // 0=Q 1=K 2=V (uniform per block)
        if (region < 2) {
            const float scale = (region == 0) ? QSCALE : 1.0f;
            ushort_t* H = (region == 0) ? Qh : Kh;
            ushort_t* L = (region == 0) ? Ql : Kl;
            const int head = ((m0 & 1023) >> 6) + wr;
            const size_t bh_base = (size_t)(b * HEADS + head) * NN;
#pragma unroll
            for (int fj = 0; fj < 2; ++fj) {
                const size_t rowb = (bh_base + nn + fj * 32) * DHEAD;
#pragma unroll
                for (int fi = 0; fi < 2; ++fi) {
                    const int d0 = fi * 32 + 4 * hi5;
#pragma unroll
                    for (int g = 0; g < 4; ++g) {
                        ushort4v hv, lv;
#pragma unroll
                        for (int i = 0; i < 4; ++i) {
                            float f = acc[fi][fj][4 * g + i] * scale;
                            ushort_t h2 = f2bf(f);
                            hv[i] = h2;
                            lv[i] = f2bf(f - bf2f(h2));
                        }
                        *(ushort4v*)(H + rowb + d0 + 8 * g) = hv;
                        *(ushort4v*)(L + rowb + d0 + 8 * g) = lv;
                    }
                }
            }
        } else {
            const int ch0 = (m0 - 2048) + wr * 64;
#pragma unroll
            for (int fi = 0; fi < 2; ++fi)
#pragma unroll
                for (int fj = 0; fj < 2; ++fj)
#pragma unroll
                    for (int r = 0; r < 16; ++r) {
                        const int ch = ch0 + fi * 32 + (r & 3) + 8 * (r >> 2) + 4 * hi5;
                        const size_t idx = ((size_t)b * HDIM + ch) * NN + nn + fj * 32;
                        float f = acc[fi][fj][r];
                        ushort_t h2 = f2bf(f);
                        Vh[idx] = h2;
                        Vl[idx] = f2bf(f - bf2f(h2));
                    }
        }
    } else {
#pragma unroll
        for (int fi = 0; fi < 2; ++fi)
#pragma unroll
            for (int fj = 0; fj < 2; ++fj)
#pragma unroll
                for (int r = 0; r < 16; ++r) {
                    const int mrow = m0 + wr * 64 + fi * 32 + (r & 3) + 8 * (r >> 2) + 4 * hi5;
                    outF[((size_t)b * CIN + mrow) * NN + nn + fj * 32] =
                        acc[fi][fj][r] + bias[mrow];
                }
    }
}

// ---------------- MFMA flash attention (no LDS, no barriers) ----------------
__global__ __launch_bounds__(256) void attn_mfma(
    const ushort_t* __restrict__ Qh, const ushort_t* __restrict__ Ql,
    const ushort_t* __restrict__ Kh, const ushort_t* __restrict__ Kl,
    const ushort_t* __restrict__ Vh, const ushort_t* __restrict__ Vl,
    ushort_t* __restrict__ aoth, ushort_t* __restrict__ aotl) {
    const int b = blockIdx.z, h = blockIdx.y;
    const int bh = b * HEADS + h;
    const int wave = threadIdx.x >> 6;
    const int lane = threadIdx.x & 63;
    const int l31 = lane & 31;
    const int hi5 = lane >> 5;
    const int q0 = blockIdx.x * 128 + wave * 32;

    bf16x8 qfh[4], qfl[4];
    {
        const ushort_t* qb  = Qh + ((size_t)bh * NN + q0 + l31) * DHEAD + hi5 * 8;
        const ushort_t* ql_ = Ql + ((size_t)bh * NN + q0 + l31) * DHEAD + hi5 * 8;
#pragma unroll
        for (int c = 0; c < 4; ++c) {
            qfh[c] = *(const bf16x8*)(qb + c * 16);
            qfl[c] = *(const bf16x8*)(ql_ + c * 16);
        }
    }

    f32x16 o0, o1;
#pragma unroll
    for (int r = 0; r < 16; ++r) { o0[r] = 0.f; o1[r] = 0.f; }
    float m = -1e30f, l = 0.f;

    const ushort_t* kbh = Kh + ((size_t)bh * NN + l31) * DHEAD + hi5 * 8;
    const ushort_t* kbl = Kl + ((size_t)bh * NN + l31) * DHEAD + hi5 * 8;
    const ushort_t* vbh = Vh + (size_t)bh * DHEAD * NN + hi5 * 8;
    const ushort_t* vbl = Vl + (size_t)bh * DHEAD * NN + hi5 * 8;

    for (int j0 = 0; j0 < NN; j0 += 32) {
        f32x16 s;
#pragma unroll
        for (int r = 0; r < 16; ++r) s[r] = 0.f;
#pragma unroll
        for (int c = 0; c < 4; ++c) {
            bf16x8 kh_ = *(const bf16x8*)(kbh + (size_t)j0 * DHEAD + c * 16);
            bf16x8 kl_ = *(const bf16x8*)(kbl + (size_t)j0 * DHEAD + c * 16);
            s = mfma32(kh_, qfh[c], s);
            s = mfma32(kl_, qfh[c], s);
            s = mfma32(kh_, qfl[c], s);
        }

        float tmax = s[0];
#pragma unroll
        for (int r = 1; r < 16; ++r) tmax = fmaxf(tmax, s[r]);
        tmax = fmaxf(tmax, __shfl_xor(tmax, 32));
        if (!__all(tmax - m <= 8.0f)) {
            float mn = fmaxf(m, tmax);
            float corr = __expf(m - mn);
            l *= corr;
#pragma unroll
            for (int r = 0; r < 16; ++r) { o0[r] *= corr; o1[r] *= corr; }
            m = mn;
        }
        float p[16];
        float ps = 0.f;
#pragma unroll
        for (int r = 0; r < 16; ++r) { p[r] = __expf(s[r] - m); ps += p[r]; }
        l += ps + __shfl_xor(ps, 32);

        unsigned phw[8], plw[8];
#pragma unroll
        for (int rp = 0; rp < 8; ++rp) {
            float a = p[2 * rp], c2 = p[2 * rp + 1];
            ushort_t ha = f2bf(a), hb = f2bf(c2);
            phw[rp] = (unsigned)ha | ((unsigned)hb << 16);
            ushort_t la = f2bf(a - bf2f(ha)), lb = f2bf(c2 - bf2f(hb));
            plw[rp] = (unsigned)la | ((unsigned)lb << 16);
        }

#pragma unroll
        for (int jc = 0; jc < 2; ++jc) {
            unsigned P0 = phw[4 * jc + 0], P1 = phw[4 * jc + 1];
            unsigned P2 = phw[4 * jc + 2], P3 = phw[4 * jc + 3];
            unsigned L0 = plw[4 * jc + 0], L1 = plw[4 * jc + 1];
            unsigned L2 = plw[4 * jc + 2], L3 = plw[4 * jc + 3];
            unsigned sP0 = __shfl_xor((int)P0, 32), sP1 = __shfl_xor((int)P1, 32);
            unsigned sP2 = __shfl_xor((int)P2, 32), sP3 = __shfl_xor((int)P3, 32);
            unsigned sL0 = __shfl_xor((int)L0, 32), sL1 = __shfl_xor((int)L1, 32);
            unsigned sL2 = __shfl_xor((int)L2, 32), sL3 = __shfl_xor((int)L3, 32);
            U4 th, tl;
            th.u[0] = hi5 ? sP2 : P0;
            th.u[1] = hi5 ? sP3 : P1;
            th.u[2] = hi5 ? P2 : sP0;
            th.u[3] = hi5 ? P3 : sP1;
            tl.u[0] = hi5 ? sL2 : L0;
            tl.u[1] = hi5 ? sL3 : L1;
            tl.u[2] = hi5 ? L2 : sL0;
            tl.u[3] = hi5 ? L3 : sL1;
            bf16x8 pBh = th.v, pBl = tl.v;
#pragma unroll
            for (int dt = 0; dt < 2; ++dt) {
                size_t voff = (size_t)(dt * 32 + l31) * NN + j0 + jc * 16;
                bf16x8 vh_ = *(const bf16x8*)(vbh + voff);
                bf16x8 vl_ = *(const bf16x8*)(vbl + voff);
                if (dt == 0) {
                    o0 = mfma32(vh_, pBh, o0);
                    o0 = mfma32(vh_, pBl, o0);
                    o0 = mfma32(vl_, pBh, o0);
                } else {
                    o1 = mfma32(vh_, pBh, o1);
                    o1 = mfma32(vh_, pBl, o1);
                    o1 = mfma32(vl_, pBh, o1);
                }
            }
        }
    }

    // epilogue: write transposed hi/lo bf16 aot[b][n][h*64+d]
    const float invl = 1.0f / l;
    const size_t rowb = ((size_t)b * NN + q0 + l31) * HDIM + h * DHEAD;
#pragma unroll
    for (int dt = 0; dt < 2; ++dt)
#pragma unroll
        for (int g = 0; g < 4; ++g) {
            ushort4v hv, lv;
#pragma unroll
            for (int i = 0; i < 4; ++i) {
                float f = (dt ? o1[4 * g + i] : o0[4 * g + i]) * invl;
                ushort_t h2 = f2bf(f);
                hv[i] = h2;
                lv[i] = f2bf(f - bf2f(h2));
            }
            size_t o = rowb + dt * 32 + 8 * g + 4 * hi5;
            *(ushort4v*)(aoth + o) = hv;
            *(ushort4v*)(aotl + o) = lv;
        }
}

// ---------------- launch ----------------
extern "C" void kernel_launch(void* const* d_in, const int* in_sizes, int n_in,
                              void* d_out, int out_size, void* d_ws, size_t ws_size,
                              hipStream_t stream) {
    const float* x     = (const float*)d_in[0];
    const float* w_qkv = (const float*)d_in[1];
    const float* w_out = (const float*)d_in[2];
    const float* b_out = (const float*)d_in[3];
    float* out = (float*)d_out;

    ushort_t* ws_u = (ushort_t*)d_ws;
    // persistent through attention:
    ushort_t* Qh = ws_u;
    ushort_t* Ql = Qh + QSZ;
    ushort_t* Kh = Ql + QSZ;
    ushort_t* Kl = Kh + QSZ;
    ushort_t* Vh = Kl + QSZ;
    ushort_t* Vl = Vh + QSZ;
    // shared region (16.78 MB): wq hi/lo (phase A), then aot hi/lo (phase B)
    ushort_t* shared_u = ws_u + 6 * QSZ;
    ushort_t* wqh = shared_u;
    ushort_t* wql = wqh + (size_t)O3 * CIN;
    ushort_t* aoth = shared_u;
    ushort_t* aotl = aoth + (size_t)BATCH * NN * HDIM;
    // wo hi/lo into dead Q region (phase B)
    ushort_t* woh = ws_u;
    ushort_t* wol = woh + (size_t)CIN * HDIM;
    // xt scratch lives inside d_out (exactly out_size bytes), dead before final GEMM
    ushort_t* xth = (ushort_t*)d_out;
    ushort_t* xtl = xth + (size_t)BATCH * NN * CIN;

    if (ws_size < (6 * QSZ + 2 * (size_t)BATCH * NN * CIN) * sizeof(ushort_t)) return;

    // 1) weight + input conversions
    convert_split<<<1536, 256, 0, stream>>>(w_qkv, wqh, wql, O3 * CIN / 8);
    transpose_cvt<<<dim3(NN / 32, CIN / 32, BATCH), 256, 0, stream>>>(x, xth, xtl);

    // 2) QKV projection (MFMA split-bf16) -> Q/K/V hi/lo
    gemm_mfma<0><<<dim3(NN / 128, O3 / 128, BATCH), 256, 0, stream>>>(
        wqh, wql, xth, xtl, nullptr, nullptr, Qh, Ql, Kh, Kl, Vh, Vl);

    // 3) flash attention -> aot hi/lo [b][n][ch] (overwrites wq region)
    attn_mfma<<<dim3(NN / 128, HEADS, BATCH), 256, 0, stream>>>(
        Qh, Ql, Kh, Kl, Vh, Vl, aoth, aotl);

    // 4) w_out conversion into dead Q region
    convert_split<<<512, 256, 0, stream>>>(w_out, woh, wol, CIN * HDIM / 8);

    // 5) output projection (MFMA split-bf16) + bias -> out f32 (overwrites xt)
    gemm_mfma<1><<<dim3(NN / 128, HDIM / 128, BATCH), 256, 0, stream>>>(
        woh, wol, aoth, aotl, b_out, out, nullptr, nullptr, nullptr, nullptr,
        nullptr, nullptr);
}